// Round 6
// baseline (112.991 us; speedup 1.0000x reference)
//
#include <hip/hip_runtime.h>
#include <math.h>

namespace {

constexpr int INF = 32;
constexpr int H   = 128;
constexpr int HH  = 64;
constexpr int SPW = 4;     // samples per wave; block = 1 wave
constexpr float LNEPS = 1e-5f;

template<int V> struct ic { static constexpr int value = V; };

template<int N, int I = 0, class F>
__device__ __forceinline__ void sfor(F&& f) {
    if constexpr (I < N) { f(ic<I>{}); sfor<N, I + 1>(f); }
}

__device__ __forceinline__ float elu1(float v) {
    return v > 0.f ? v : (__expf(v) - 1.f);
}

// split-K combine: sum the 4 ks-group partials (xor 16 within half, xor 32 across)
__device__ __forceinline__ float bfly(float v) {
    v += __shfl_xor(v, 16, 64);
    v += __shfl_xor(v, 32, 64);
    return v;
}

// reduce across the 16 lanes of a ks-group (values replicated across groups)
__device__ __forceinline__ float red16(float v) {
    v += __shfl_xor(v, 1, 64);
    v += __shfl_xor(v, 2, 64);
    v += __shfl_xor(v, 4, 64);
    v += __shfl_xor(v, 8, 64);
    return v;
}

// ds_swizzle BitMode: src_lane(5LSB) = ((i & and) | or) ^ xor ; pattern = (xor<<10)|(or<<5)|and
// NOTE: the swizzled register must hold the SAME logical slot on every lane
// (slot choice may depend only on compile-time constants, never on lane id).
#define SWZ(v, pat) __int_as_float(__builtin_amdgcn_ds_swizzle(__float_as_int(v), (pat)))

// select t[2*ks + JP] from the 8 replicated col-slots (static cndmask tree, rule #20)
template<int JP>
__device__ __forceinline__ float selks(const float (&tj)[8], int ks) {
    const float a = (ks & 2) ? tj[JP + 4] : tj[JP];
    const float b = (ks & 2) ? tj[JP + 6] : tj[JP + 2];
    return (ks & 1) ? b : a;
}

// t[s][j] += sum_{rg<NROWS} act(s,rg) * Wthr[rg*LDW + j*16]
// Wthr pre-offset to this thread's (row0, col). 4-row register-double-buffered
// weight prefetch; everything statically indexed.
template<int NROWS, int NC, int LDW, class ActF>
__device__ __forceinline__ void gemm_core(const float* __restrict__ Wthr,
                                          ActF&& act, float (&t)[SPW][NC])
{
    constexpr int NCH = NROWS / 4;
    float wa[4][NC], wb[4][NC];
    sfor<4>([&](auto R) { sfor<NC>([&](auto J) {
        wa[R.value][J.value] = Wthr[R.value * LDW + J.value * 16];
    }); });
    sfor<NCH>([&](auto CH) {
        constexpr int ch = decltype(CH)::value;
        auto step = [&](auto& cur, auto& nxt) {
            if constexpr (ch + 1 < NCH) {
                sfor<4>([&](auto R) { sfor<NC>([&](auto J) {
                    nxt[R.value][J.value] =
                        Wthr[((ch + 1) * 4 + R.value) * LDW + J.value * 16];
                }); });
            }
            sfor<4>([&](auto R) {
                constexpr int rg = ch * 4 + decltype(R)::value;
                float a[SPW];
                sfor<SPW>([&](auto S) { a[S.value] = act(S, ic<rg>{}); });
                sfor<NC>([&](auto J) { sfor<SPW>([&](auto S) {
                    t[S.value][J.value] += a[S.value] * cur[R.value][J.value];
                }); });
            });
        };
        if constexpr ((ch & 1) == 0) step(wa, wb); else step(wb, wa);
    });
}

// Distributed activation layout between layers:
//   lane (ks = lane>>4, c = lane&15), slot A/B (j' = 0/1) holds h[s][32*ks + 16*j' + c].
// Own-group fetch of absolute row 32*ks + 16*slot + rg (slot compile-time):
//   src lane = (i&16)|rg per 32-half  ->  SWZ(slotReg, (rg<<5)|0x10).

__global__ __launch_bounds__(64) void fused_sthgat(
    const float* __restrict__ x, const int* __restrict__ sid,
    const float* __restrict__ Wp, const float* __restrict__ bp,
    const float* __restrict__ emb, const float* __restrict__ gatW,
    const float* __restrict__ W1, const float* __restrict__ b1,
    const float* __restrict__ g1, const float* __restrict__ be1,
    const float* __restrict__ W2, const float* __restrict__ b2,
    const float* __restrict__ g2, const float* __restrict__ be2,
    const float* __restrict__ Wo, const float* __restrict__ bo,
    float* __restrict__ out)
{
    const int lane = threadIdx.x;
    const int ks = lane >> 4;       // K-split group 0..3
    const int c  = lane & 15;       // column residue; thread cols = c + 16*j
    const int sbase = blockIdx.x * SPW;

    // preload x (lane l holds x[s][l&31], duplicated halves) and emb (lane l -> emb[s][l])
    float xr[SPW], embr[SPW];
    sfor<SPW>([&](auto S) {
        constexpr int s = decltype(S)::value;
        xr[s] = x[(size_t)(sbase + s) * INF + (lane & 31)];
        const int st = sid[sbase + s];
        embr[s] = emb[(size_t)st * HH + lane];
    });

    float hA[SPW], hB[SPW];   // distributed h (slots j'=0,1)

    // ---- Wp: h0 = x @ Wp + bp  (rows 0..31; only ks<2 groups accumulate) ----
    {
        float t8[SPW][8] = {};
        if (ks < 2) {
            const float* wT = Wp + (size_t)(16 * (ks & 1)) * H + c;
            gemm_core<16, 8, H>(wT, [&](auto S, auto RG) {
                // x[s][16*(ks&1) + rg]: src lane = (i&16)|rg within each half
                return SWZ(xr[S.value], ((decltype(RG)::value & 15) << 5) | 0x10);
            }, t8);
        }
        float bpv[8];
        sfor<8>([&](auto J) { bpv[J.value] = bp[c + 16 * J.value]; });
        sfor<SPW>([&](auto S) {
            sfor<8>([&](auto J) {
                t8[S.value][J.value] = bfly(t8[S.value][J.value]) + bpv[J.value];
            });
            hA[S.value] = selks<0>(t8[S.value], ks);
            hB[S.value] = selks<1>(t8[S.value], ks);
        });
    }

    // ---- GAT x2 (node-collapsed): h += elu(h @ gWi) ----
    for (int gi = 0; gi < 2; ++gi) {
        const float* wT = gatW + (size_t)gi * H * H + (size_t)(32 * ks) * H + c;
        float t8[SPW][8] = {};
        gemm_core<32, 8, H>(wT, [&](auto S, auto RG) {
            constexpr int rg = decltype(RG)::value;
            float v;
            if constexpr (rg < 16) v = SWZ(hA[S.value], ((rg & 15) << 5) | 0x10);
            else                   v = SWZ(hB[S.value], ((rg & 15) << 5) | 0x10);
            return v;
        }, t8);
        sfor<SPW>([&](auto S) {
            sfor<8>([&](auto J) {
                t8[S.value][J.value] = bfly(t8[S.value][J.value]);
            });
            hA[S.value] += elu1(selks<0>(t8[S.value], ks));
            hB[S.value] += elu1(selks<1>(t8[S.value], ks));
        });
    }

    // ---- W1: u = [h, emb] @ W1 + b1 ; LN1 + relu ----
    // K-partition (slot uniform per chunk — FIX for round-5 bug):
    //   ks covers local h rows 64*(ks>>1) + 32*(ks&1) + {0..31}:
    //     first 16 rows are slot A of src lane (i&16)|rg, next 16 slot B.
    float zA[SPW], zB[SPW];
    {
        float t8[SPW][8] = {};
        const int khalf = ks >> 1;
        const int kodd  = ks & 1;
        const float* wTA = W1 + (size_t)(64 * khalf + 32 * kodd) * H + c;
        gemm_core<16, 8, H>(wTA, [&](auto S, auto RG) {
            // h[64*khalf + 32*kodd + rg] = slot A of lane (i&16)|rg
            return SWZ(hA[S.value], ((decltype(RG)::value & 15) << 5) | 0x10);
        }, t8);
        const float* wTB = wTA + 16 * H;
        gemm_core<16, 8, H>(wTB, [&](auto S, auto RG) {
            // h[64*khalf + 32*kodd + 16 + rg] = slot B of lane (i&16)|rg
            return SWZ(hB[S.value], ((decltype(RG)::value & 15) << 5) | 0x10);
        }, t8);
        const float* wT2 = W1 + (size_t)(128 + 16 * ks) * H + c;
        gemm_core<16, 8, H>(wT2, [&](auto S, auto RG) {
            // emb[s][16*ks + rg]: own-group pattern on the 64-wide embr
            return SWZ(embr[S.value], ((decltype(RG)::value & 15) << 5) | 0x10);
        }, t8);

        float b1v[8], g1v[8], be1v[8];
        sfor<8>([&](auto J) {
            b1v[J.value]  = b1[c + 16 * J.value];
            g1v[J.value]  = g1[c + 16 * J.value];
            be1v[J.value] = be1[c + 16 * J.value];
        });
        sfor<SPW>([&](auto S) {
            float su = 0.f, sq = 0.f;
            sfor<8>([&](auto J) {
                const float u = bfly(t8[S.value][J.value]) + b1v[J.value];
                t8[S.value][J.value] = u;
                su += u; sq += u * u;
            });
            su = red16(su); sq = red16(sq);
            const float m   = su * (1.f / H);
            const float var = sq * (1.f / H) - m * m;
            const float rs  = rsqrtf(var + LNEPS);
            sfor<8>([&](auto J) {
                t8[S.value][J.value] = fmaxf(
                    (t8[S.value][J.value] - m) * rs * g1v[J.value] + be1v[J.value], 0.f);
            });
            zA[S.value] = selks<0>(t8[S.value], ks);
            zB[S.value] = selks<1>(t8[S.value], ks);
        });
    }

    // ---- W2: v = z1 @ W2 + b2 ; LN2 + relu ; out = z2 @ Wo + bo ----
    {
        float t4[SPW][4] = {};
        const float* wT = W2 + (size_t)(32 * ks) * HH + c;
        gemm_core<32, 4, HH>(wT, [&](auto S, auto RG) {
            constexpr int rg = decltype(RG)::value;
            float v;
            if constexpr (rg < 16) v = SWZ(zA[S.value], ((rg & 15) << 5) | 0x10);
            else                   v = SWZ(zB[S.value], ((rg & 15) << 5) | 0x10);
            return v;
        }, t4);

        float b2v[4], g2v[4], be2v[4], wov[4];
        sfor<4>([&](auto J) {
            b2v[J.value]  = b2[c + 16 * J.value];
            g2v[J.value]  = g2[c + 16 * J.value];
            be2v[J.value] = be2[c + 16 * J.value];
            wov[J.value]  = Wo[c + 16 * J.value];
        });
        const float bov = bo[0];
        sfor<SPW>([&](auto S) {
            float su = 0.f, sq = 0.f;
            sfor<4>([&](auto J) {
                const float v = bfly(t4[S.value][J.value]) + b2v[J.value];
                t4[S.value][J.value] = v;
                su += v; sq += v * v;
            });
            su = red16(su); sq = red16(sq);
            const float m   = su * (1.f / HH);
            const float var = sq * (1.f / HH) - m * m;
            const float rs  = rsqrtf(var + LNEPS);
            float po = 0.f;
            sfor<4>([&](auto J) {
                po += fmaxf((t4[S.value][J.value] - m) * rs * g2v[J.value]
                            + be2v[J.value], 0.f) * wov[J.value];
            });
            po = red16(po);
            if (lane == 0) out[sbase + S.value] = po + bov;
        });
    }
}

}  // namespace

extern "C" void kernel_launch(void* const* d_in, const int* in_sizes, int n_in,
                              void* d_out, int out_size, void* d_ws, size_t ws_size,
                              hipStream_t stream)
{
    const float* x    = (const float*)d_in[0];
    const int*   sid  = (const int*)d_in[1];
    // d_in[2] edge_index, d_in[3] edge_weight, d_in[8] gat_a: unused —
    // node-uniform broadcast + row-softmax makes the GAT aggregation collapse
    // to elu(h @ W) independent of the graph.
    const float* Wp   = (const float*)d_in[4];
    const float* bp   = (const float*)d_in[5];
    const float* emb  = (const float*)d_in[6];
    const float* gatW = (const float*)d_in[7];
    const float* W1   = (const float*)d_in[9];
    const float* b1   = (const float*)d_in[10];
    const float* g1   = (const float*)d_in[11];
    const float* be1  = (const float*)d_in[12];
    const float* W2   = (const float*)d_in[13];
    const float* b2   = (const float*)d_in[14];
    const float* g2   = (const float*)d_in[15];
    const float* be2  = (const float*)d_in[16];
    const float* Wo   = (const float*)d_in[17];
    const float* bo   = (const float*)d_in[18];
    float* out = (float*)d_out;

    // 1024 single-wave blocks -> 4 blocks/CU -> 1 wave/SIMD on every SIMD.
    // No LDS, no barriers: waves fully independent; weights stream from L2.
    dim3 grid(4096 / SPW);
    dim3 block(64);
    hipLaunchKernelGGL(fused_sthgat, grid, block, 0, stream,
                       x, sid, Wp, bp, emb, gatW, W1, b1, g1, be1,
                       W2, b2, g2, be2, Wo, bo, out);
}

// Round 8
// 108.401 us; speedup vs baseline: 1.0423x; 1.0423x over previous
//
#include <hip/hip_runtime.h>
#include <math.h>

namespace {

constexpr int INF = 32;
constexpr int H   = 128;
constexpr int HH  = 64;
constexpr int ZD  = 192;   // H + HH
constexpr int SPB = 4;     // samples per block
constexpr float LNEPS = 1e-5f;

template<int V> struct ic { static constexpr int value = V; };

template<int N, int I = 0, class F>
__device__ __forceinline__ void sfor(F&& f) {
    if constexpr (I < N) { f(ic<I>{}); sfor<N, I + 1>(f); }
}

__device__ __forceinline__ float elu1(float v) {
    return v > 0.f ? v : (__expf(v) - 1.f);
}

// t[s].{x,y} += sum_{r<DKq} act[s*ZD + r] * W0[r*LDW + {0,1}]
// W0 pre-offset to &W[row0*LDW + 2*c] (adjacent column pair -> coalesced
// float2 loads). 8-row chunks, triple-buffered: chunk loads are issued two
// compute-blocks (~256 issue-cycles) before first use, covering L2 latency.
// All indexing static (rule #20). act reads are wave-uniform ds_read_b128.
template<int DKq, int LDW>
__device__ __forceinline__ void gemm_f2(const float* __restrict__ W0,
                                        const float* __restrict__ actb,
                                        float2 (&t)[SPB])
{
    constexpr int NCH = DKq / 8;
    float2 wA[8], wB[8], wC[8];

    auto ld = [&](auto CH, float2 (&buf)[8]) {
        constexpr int ch = decltype(CH)::value;
        sfor<8>([&](auto R) {
            buf[R.value] = *reinterpret_cast<const float2*>(
                W0 + (size_t)(ch * 8 + R.value) * LDW);
        });
    };
    auto comp = [&](auto CH, float2 (&buf)[8]) {
        constexpr int ch = decltype(CH)::value;
        sfor<2>([&](auto G) {
            constexpr int g4 = decltype(G)::value;
            constexpr int r0 = ch * 8 + g4 * 4;
            float4 a[SPB];
            sfor<SPB>([&](auto S) {
                a[S.value] = *reinterpret_cast<const float4*>(
                    actb + S.value * ZD + r0);
            });
            sfor<SPB>([&](auto S) {
                constexpr int s = decltype(S)::value;
                constexpr int rb = g4 * 4;
                t[s].x += a[s].x * buf[rb + 0].x + a[s].y * buf[rb + 1].x
                        + a[s].z * buf[rb + 2].x + a[s].w * buf[rb + 3].x;
                t[s].y += a[s].x * buf[rb + 0].y + a[s].y * buf[rb + 1].y
                        + a[s].z * buf[rb + 2].y + a[s].w * buf[rb + 3].y;
            });
        });
    };

    ld(ic<0>{}, wA);
    if constexpr (NCH > 1) ld(ic<1>{}, wB);
    sfor<NCH>([&](auto CH) {
        constexpr int ch = decltype(CH)::value;
        if constexpr (ch + 2 < NCH) {
            if constexpr ((ch + 2) % 3 == 0)      ld(ic<ch + 2>{}, wA);
            else if constexpr ((ch + 2) % 3 == 1) ld(ic<ch + 2>{}, wB);
            else                                  ld(ic<ch + 2>{}, wC);
        }
        if constexpr (ch % 3 == 0)      comp(CH, wA);
        else if constexpr (ch % 3 == 1) comp(CH, wB);
        else                            comp(CH, wC);
    });
}

// scalar-column variant (for W2: 64 output cols, 1 col/thread)
template<int DKq, int LDW>
__device__ __forceinline__ void gemm_s(const float* __restrict__ W0,
                                       const float* __restrict__ actb,
                                       float (&t)[SPB])
{
    constexpr int NCH = DKq / 8;
    float wA[8], wB[8], wC[8];

    auto ld = [&](auto CH, float (&buf)[8]) {
        constexpr int ch = decltype(CH)::value;
        sfor<8>([&](auto R) {
            buf[R.value] = W0[(size_t)(ch * 8 + R.value) * LDW];
        });
    };
    auto comp = [&](auto CH, float (&buf)[8]) {
        constexpr int ch = decltype(CH)::value;
        sfor<2>([&](auto G) {
            constexpr int g4 = decltype(G)::value;
            constexpr int r0 = ch * 8 + g4 * 4;
            float4 a[SPB];
            sfor<SPB>([&](auto S) {
                a[S.value] = *reinterpret_cast<const float4*>(
                    actb + S.value * ZD + r0);
            });
            sfor<SPB>([&](auto S) {
                constexpr int s = decltype(S)::value;
                constexpr int rb = g4 * 4;
                t[s] += a[s].x * buf[rb + 0] + a[s].y * buf[rb + 1]
                      + a[s].z * buf[rb + 2] + a[s].w * buf[rb + 3];
            });
        });
    };

    ld(ic<0>{}, wA);
    if constexpr (NCH > 1) ld(ic<1>{}, wB);
    sfor<NCH>([&](auto CH) {
        constexpr int ch = decltype(CH)::value;
        if constexpr (ch + 2 < NCH) {
            if constexpr ((ch + 2) % 3 == 0)      ld(ic<ch + 2>{}, wA);
            else if constexpr ((ch + 2) % 3 == 1) ld(ic<ch + 2>{}, wB);
            else                                  ld(ic<ch + 2>{}, wC);
        }
        if constexpr (ch % 3 == 0)      comp(CH, wA);
        else if constexpr (ch % 3 == 1) comp(CH, wB);
        else                            comp(CH, wC);
    });
}

__global__ __launch_bounds__(256, 4) void fused_sthgat(
    const float* __restrict__ x, const int* __restrict__ sid,
    const float* __restrict__ Wp, const float* __restrict__ bp,
    const float* __restrict__ emb, const float* __restrict__ gatW,
    const float* __restrict__ W1, const float* __restrict__ b1,
    const float* __restrict__ g1, const float* __restrict__ be1,
    const float* __restrict__ W2, const float* __restrict__ b2,
    const float* __restrict__ g2, const float* __restrict__ be2,
    const float* __restrict__ Wo, const float* __restrict__ bo,
    float* __restrict__ out)
{
    // P2: split-K partials [kq=4][s=4][col<=128]; lanes contiguous -> conflict-free.
    __shared__ __align__(16) float P2[4 * SPB * H];
    __shared__ __align__(16) float buf0[SPB * ZD];
    __shared__ __align__(16) float buf1[SPB * ZD];

    const int tid  = threadIdx.x;
    const int lane = tid & 63;
    const int kq   = tid >> 6;     // GEMM role: K-quarter 0..3
    const int c    = tid & 63;     // GEMM role: column pair (2c, 2c+1)
    const int sw   = tid >> 6;     // combine/LN role: sample (wave = sample)
    const int sbase = blockIdx.x * SPB;

    // ---- Wp quarter weights issued immediately; latency hides under staging ----
    float2 wp[8];
    sfor<8>([&](auto R) {
        wp[R.value] = *reinterpret_cast<const float2*>(
            Wp + (size_t)(kq * 8 + R.value) * H + 2 * c);
    });
    const float2 bpv = *reinterpret_cast<const float2*>(bp + 2 * c);

    // ---- stage x: 4 samples x 32 floats into buf0 (stride ZD) ----
    if (tid < SPB * INF) {
        buf0[(tid >> 5) * ZD + (tid & 31)] = x[(size_t)sbase * INF + tid];
    }
    __syncthreads();

    // ---- Wp: h0 = x @ Wp + bp  (buf0 -> buf1) ----
    {
        float2 t[SPB] = {};
        const float* actb = buf0 + kq * 8;
        sfor<2>([&](auto G) {
            constexpr int g4 = decltype(G)::value;
            float4 a[SPB];
            sfor<SPB>([&](auto S) {
                a[S.value] = *reinterpret_cast<const float4*>(
                    actb + S.value * ZD + g4 * 4);
            });
            sfor<SPB>([&](auto S) {
                constexpr int s = decltype(S)::value;
                constexpr int rb = g4 * 4;
                t[s].x += a[s].x * wp[rb + 0].x + a[s].y * wp[rb + 1].x
                        + a[s].z * wp[rb + 2].x + a[s].w * wp[rb + 3].x;
                t[s].y += a[s].x * wp[rb + 0].y + a[s].y * wp[rb + 1].y
                        + a[s].z * wp[rb + 2].y + a[s].w * wp[rb + 3].y;
            });
        });
        sfor<SPB>([&](auto S) {
            *reinterpret_cast<float2*>(
                P2 + kq * (SPB * H) + S.value * H + 2 * c) = t[S.value];
        });
        __syncthreads();
        float2 v = bpv;
        sfor<4>([&](auto K) {
            const float2 p = *reinterpret_cast<const float2*>(
                P2 + decltype(K)::value * (SPB * H) + sw * H + 2 * c);
            v.x += p.x; v.y += p.y;
        });
        *reinterpret_cast<float2*>(buf1 + sw * ZD + 2 * c) = v;
        __syncthreads();
    }

    // ---- GAT1: h = h + elu(h @ gW0)  (buf1 -> buf0) ----
    {
        float2 t[SPB] = {};
        gemm_f2<32, H>(gatW + (size_t)(kq * 32) * H + 2 * c, buf1 + kq * 32, t);
        sfor<SPB>([&](auto S) {
            *reinterpret_cast<float2*>(
                P2 + kq * (SPB * H) + S.value * H + 2 * c) = t[S.value];
        });
        __syncthreads();
        float2 v = {0.f, 0.f};
        sfor<4>([&](auto K) {
            const float2 p = *reinterpret_cast<const float2*>(
                P2 + decltype(K)::value * (SPB * H) + sw * H + 2 * c);
            v.x += p.x; v.y += p.y;
        });
        const float2 hp = *reinterpret_cast<const float2*>(buf1 + sw * ZD + 2 * c);
        float2 o; o.x = hp.x + elu1(v.x); o.y = hp.y + elu1(v.y);
        *reinterpret_cast<float2*>(buf0 + sw * ZD + 2 * c) = o;
        __syncthreads();
    }

    // ---- GAT2: h = h + elu(h @ gW1)  (buf0 -> buf1) + emb concat ----
    {
        float2 t[SPB] = {};
        gemm_f2<32, H>(gatW + (size_t)H * H + (size_t)(kq * 32) * H + 2 * c,
                       buf0 + kq * 32, t);
        sfor<SPB>([&](auto S) {
            *reinterpret_cast<float2*>(
                P2 + kq * (SPB * H) + S.value * H + 2 * c) = t[S.value];
        });
        __syncthreads();
        float2 v = {0.f, 0.f};
        sfor<4>([&](auto K) {
            const float2 p = *reinterpret_cast<const float2*>(
                P2 + decltype(K)::value * (SPB * H) + sw * H + 2 * c);
            v.x += p.x; v.y += p.y;
        });
        const float2 hp = *reinterpret_cast<const float2*>(buf0 + sw * ZD + 2 * c);
        float2 o; o.x = hp.x + elu1(v.x); o.y = hp.y + elu1(v.y);
        *reinterpret_cast<float2*>(buf1 + sw * ZD + 2 * c) = o;
        // z = [h2, emb[sid]]: wave sw fills its sample's 64 emb slots (lane == c)
        {
            const int st = sid[sbase + sw];
            buf1[sw * ZD + H + c] = emb[(size_t)st * HH + c];
        }
        __syncthreads();
    }

    // ---- W1: u = z @ W1 + b1 ; LN1 (in-wave) + relu  (buf1 -> buf0) ----
    {
        const float2 b1v  = *reinterpret_cast<const float2*>(b1 + 2 * c);
        const float2 g1v  = *reinterpret_cast<const float2*>(g1 + 2 * c);
        const float2 be1v = *reinterpret_cast<const float2*>(be1 + 2 * c);
        float2 t[SPB] = {};
        gemm_f2<48, H>(W1 + (size_t)(kq * 48) * H + 2 * c, buf1 + kq * 48, t);
        sfor<SPB>([&](auto S) {
            *reinterpret_cast<float2*>(
                P2 + kq * (SPB * H) + S.value * H + 2 * c) = t[S.value];
        });
        __syncthreads();
        float u0 = b1v.x, u1 = b1v.y;
        sfor<4>([&](auto K) {
            const float2 p = *reinterpret_cast<const float2*>(
                P2 + decltype(K)::value * (SPB * H) + sw * H + 2 * c);
            u0 += p.x; u1 += p.y;
        });
        // LN over 128 channels; wave = sample, 2 adjacent channels/lane
        float su = u0 + u1;
        float sq = u0 * u0 + u1 * u1;
#pragma unroll
        for (int off = 32; off >= 1; off >>= 1) {
            su += __shfl_xor(su, off, 64);
            sq += __shfl_xor(sq, off, 64);
        }
        const float m   = su * (1.f / H);
        const float var = sq * (1.f / H) - m * m;
        const float rs  = rsqrtf(var + LNEPS);
        float2 z;
        z.x = fmaxf((u0 - m) * rs * g1v.x + be1v.x, 0.f);
        z.y = fmaxf((u1 - m) * rs * g1v.y + be1v.y, 0.f);
        *reinterpret_cast<float2*>(buf0 + sw * ZD + 2 * c) = z;
        __syncthreads();
    }

    // ---- W2: v = z1 @ W2 + b2 ; LN2 (in-wave) ; out = z2 @ Wo + bo ----
    {
        const float b2v  = b2[c];
        const float g2v  = g2[c];
        const float be2v = be2[c];
        const float wov  = Wo[c];
        const float bov  = bo[0];
        float t[SPB] = {};
        gemm_s<32, HH>(W2 + (size_t)(kq * 32) * HH + c, buf0 + kq * 32, t);
        sfor<SPB>([&](auto S) {
            P2[kq * (SPB * HH) + S.value * HH + c] = t[S.value];
        });
        __syncthreads();
        float v = b2v;
        sfor<4>([&](auto K) {
            v += P2[decltype(K)::value * (SPB * HH) + sw * HH + c];
        });
        float su = v, sq = v * v;
#pragma unroll
        for (int off = 32; off >= 1; off >>= 1) {
            su += __shfl_xor(su, off, 64);
            sq += __shfl_xor(sq, off, 64);
        }
        const float m   = su * (1.f / HH);
        const float var = sq * (1.f / HH) - m * m;
        const float rs  = rsqrtf(var + LNEPS);
        const float z2  = fmaxf((v - m) * rs * g2v + be2v, 0.f);
        float po = z2 * wov;
#pragma unroll
        for (int off = 32; off >= 1; off >>= 1) po += __shfl_xor(po, off, 64);
        if (lane == 0) out[sbase + sw] = po + bov;
    }
}

}  // namespace

extern "C" void kernel_launch(void* const* d_in, const int* in_sizes, int n_in,
                              void* d_out, int out_size, void* d_ws, size_t ws_size,
                              hipStream_t stream)
{
    const float* x    = (const float*)d_in[0];
    const int*   sid  = (const int*)d_in[1];
    // d_in[2] edge_index, d_in[3] edge_weight, d_in[8] gat_a: unused —
    // node-uniform broadcast + row-softmax makes the GAT aggregation collapse
    // to elu(h @ W) independent of the graph.
    const float* Wp   = (const float*)d_in[4];
    const float* bp   = (const float*)d_in[5];
    const float* emb  = (const float*)d_in[6];
    const float* gatW = (const float*)d_in[7];
    const float* W1   = (const float*)d_in[9];
    const float* b1   = (const float*)d_in[10];
    const float* g1   = (const float*)d_in[11];
    const float* be1  = (const float*)d_in[12];
    const float* W2   = (const float*)d_in[13];
    const float* b2   = (const float*)d_in[14];
    const float* g2   = (const float*)d_in[15];
    const float* be2  = (const float*)d_in[16];
    const float* Wo   = (const float*)d_in[17];
    const float* bo   = (const float*)d_in[18];
    float* out = (float*)d_out;

    // 1024 blocks x 4 waves = 4 blocks/CU = 4 waves/SIMD; 4 independent
    // barrier domains per CU.
    dim3 grid(4096 / SPB);
    dim3 block(256);
    hipLaunchKernelGGL(fused_sthgat, grid, block, 0, stream,
                       x, sid, Wp, bp, emb, gatW, W1, b1, g1, be1,
                       W2, b2, g2, be2, Wo, bo, out);
}

// Round 9
// 101.743 us; speedup vs baseline: 1.1106x; 1.0654x over previous
//
#include <hip/hip_runtime.h>
#include <math.h>

namespace {

constexpr int SPW  = 8;     // real samples per wave (MFMA M=16, rows 8..15 padded)
constexpr int ACTW = 196;   // LDS row stride (floats): 16B-aligned rows, 2-way banks
constexpr float LNEPS = 1e-5f;

typedef __attribute__((ext_vector_type(8))) __bf16 bf16x8;
typedef __attribute__((ext_vector_type(4))) float  f32x4;

template<int V> struct ic { static constexpr int value = V; };

template<int N, int I = 0, class F>
__device__ __forceinline__ void sfor(F&& f) {
    if constexpr (I < N) { f(ic<I>{}); sfor<N, I + 1>(f); }
}

__device__ __forceinline__ float elu1(float v) {
    return v > 0.f ? v : (__expf(v) - 1.f);
}

// ---------------- weight pack kernel ----------------
// Frag f (0..135), lane l holds W[kt*32 + 8*(l>>4) + e][nt*16 + (l&15)], e=0..7,
// as bf16x8 at wsf + (f*64 + l)*8.  Frag map:
//   0..7    Wp   (K=32,  kt=0,  nt=f,          N=128)
//   8..39   gat0 (K=128, kt=r>>3, nt=r&7,      N=128)
//   40..71  gat1
//   72..119 W1   (K=192, kt=r/8, nt=r%8,       N=128)
//   120..135 W2  (K=128, kt=r>>2, nt=r&3,      N=64)
__global__ __launch_bounds__(64) void pack_weights(
    const float* __restrict__ Wp, const float* __restrict__ gatW,
    const float* __restrict__ W1, const float* __restrict__ W2,
    __bf16* __restrict__ wsf)
{
    const int f = blockIdx.x;
    const int l = threadIdx.x;
    const float* src; int kt, nt, N;
    if (f < 8)        { src = Wp;            kt = 0;            nt = f;            N = 128; }
    else if (f < 40)  { int r = f - 8;  src = gatW;         kt = r >> 3; nt = r & 7; N = 128; }
    else if (f < 72)  { int r = f - 40; src = gatW + 16384; kt = r >> 3; nt = r & 7; N = 128; }
    else if (f < 120) { int r = f - 72; src = W1;           kt = r / 8;  nt = r % 8; N = 128; }
    else              { int r = f - 120; src = W2;          kt = r >> 2; nt = r & 3; N = 64;  }
    const int k0 = kt * 32 + (l >> 4) * 8;
    const int n  = nt * 16 + (l & 15);
    bf16x8 v;
    sfor<8>([&](auto E) {
        v[E.value] = (__bf16)src[(size_t)(k0 + E.value) * N + n];
    });
    *reinterpret_cast<bf16x8*>(wsf + ((size_t)f * 64 + l) * 8) = v;
}

// ---------------- main fused kernel ----------------
__global__ __launch_bounds__(64) void mfma_fused(
    const float* __restrict__ x, const int* __restrict__ sid,
    const __bf16* __restrict__ wsf,
    const float* __restrict__ bp, const float* __restrict__ emb,
    const float* __restrict__ b1, const float* __restrict__ g1,
    const float* __restrict__ be1,
    const float* __restrict__ b2, const float* __restrict__ g2,
    const float* __restrict__ be2,
    const float* __restrict__ Wo, const float* __restrict__ bo,
    float* __restrict__ out)
{
    __shared__ float act[16 * ACTW];

    const int l  = threadIdx.x;
    const int gq = l >> 4;      // lane group 0..3
    const int j  = l & 15;      // MFMA col / A-row residue
    const int sbase = blockIdx.x * SPW;

    // ---- stage x: rows 0..7 real, rows 8..15 zero ----
    {
        const int s = l >> 2, ch = l & 3;   // 16 rows x 4 chunks of 8 floats
        float4 v0 = {0.f, 0.f, 0.f, 0.f}, v1 = v0;
        if (s < SPW) {
            const float* xp = x + (size_t)(sbase + s) * 32 + ch * 8;
            v0 = *reinterpret_cast<const float4*>(xp);
            v1 = *reinterpret_cast<const float4*>(xp + 4);
        }
        float* dst = act + s * ACTW + ch * 8;
        *reinterpret_cast<float4*>(dst)     = v0;
        *reinterpret_cast<float4*>(dst + 4) = v1;
    }

    // GEMM over pre-packed fragments: acc[nt] += A(act) * B(frag)
    auto gemm = [&]<int NKT, int NNT>(ic<NKT>, ic<NNT>, int fbase, f32x4 (&acc)[NNT]) {
        const __bf16* fb = wsf + ((size_t)fbase * 64 + l) * 8;
        bf16x8 bq0[NNT], bq1[NNT];
        auto ldkt = [&](auto KT, bf16x8 (&bq)[NNT]) {
            sfor<NNT>([&](auto NT) {
                bq[NT.value] = *reinterpret_cast<const bf16x8*>(
                    fb + (size_t)(decltype(KT)::value * NNT + NT.value) * 512);
            });
        };
        auto akt = [&](auto KT) -> bf16x8 {
            const float* p = act + j * ACTW + decltype(KT)::value * 32 + gq * 8;
            const float4 f0 = *reinterpret_cast<const float4*>(p);
            const float4 f1 = *reinterpret_cast<const float4*>(p + 4);
            bf16x8 a;
            a[0] = (__bf16)f0.x; a[1] = (__bf16)f0.y; a[2] = (__bf16)f0.z; a[3] = (__bf16)f0.w;
            a[4] = (__bf16)f1.x; a[5] = (__bf16)f1.y; a[6] = (__bf16)f1.z; a[7] = (__bf16)f1.w;
            return a;
        };
        auto mm = [&](bf16x8 a, bf16x8 (&bq)[NNT]) {
            sfor<NNT>([&](auto NT) {
                acc[NT.value] = __builtin_amdgcn_mfma_f32_16x16x32_bf16(
                    a, bq[NT.value], acc[NT.value], 0, 0, 0);
            });
        };
        ldkt(ic<0>{}, bq0);
        sfor<NKT>([&](auto KT) {
            constexpr int kt = decltype(KT)::value;
            if constexpr (kt + 1 < NKT) {
                if constexpr (((kt + 1) & 1) == 0) ldkt(ic<kt + 1>{}, bq0);
                else                               ldkt(ic<kt + 1>{}, bq1);
            }
            const bf16x8 a = akt(KT);
            if constexpr ((kt & 1) == 0) mm(a, bq0); else mm(a, bq1);
        });
    };

    // write C-layout regs back to act rows (row = 4*gq + r, col = nt*16 + j)
    auto writeC = [&](f32x4 (&C)[8]) {
        sfor<8>([&](auto NT) { sfor<4>([&](auto R) {
            act[(4 * gq + R.value) * ACTW + NT.value * 16 + j] = C[NT.value][R.value];
        }); });
    };

    float bpv[8];
    sfor<8>([&](auto NT) { bpv[NT.value] = bp[NT.value * 16 + j]; });

    f32x4 hC[8];

    // ---- Wp: h0 = x @ Wp + bp ----
    {
        f32x4 acc[8] = {};
        gemm(ic<1>{}, ic<8>{}, 0, acc);
        sfor<8>([&](auto NT) { sfor<4>([&](auto R) {
            hC[NT.value][R.value] = acc[NT.value][R.value] + bpv[NT.value];
        }); });
    }
    writeC(hC);

    // ---- GAT0: h += elu(h @ gW0) ----
    {
        f32x4 acc[8] = {};
        gemm(ic<4>{}, ic<8>{}, 8, acc);
        sfor<8>([&](auto NT) { sfor<4>([&](auto R) {
            hC[NT.value][R.value] += elu1(acc[NT.value][R.value]);
        }); });
    }
    writeC(hC);

    // ---- GAT1: h += elu(h @ gW1) ----
    {
        f32x4 acc[8] = {};
        gemm(ic<4>{}, ic<8>{}, 40, acc);
        sfor<8>([&](auto NT) { sfor<4>([&](auto R) {
            hC[NT.value][R.value] += elu1(acc[NT.value][R.value]);
        }); });
    }
    writeC(hC);

    // ---- emb concat into act cols 128..191 (pad rows zero) ----
    {
        const int s = l >> 2, ch = l & 3;   // 16 rows x 4 chunks of 16 floats
        float4 e0 = {0.f,0.f,0.f,0.f}, e1 = e0, e2 = e0, e3 = e0;
        if (s < SPW) {
            const int st = sid[sbase + s];
            const float* ep = emb + (size_t)st * 64 + ch * 16;
            e0 = *reinterpret_cast<const float4*>(ep);
            e1 = *reinterpret_cast<const float4*>(ep + 4);
            e2 = *reinterpret_cast<const float4*>(ep + 8);
            e3 = *reinterpret_cast<const float4*>(ep + 12);
        }
        float* dst = act + s * ACTW + 128 + ch * 16;
        *reinterpret_cast<float4*>(dst)      = e0;
        *reinterpret_cast<float4*>(dst + 4)  = e1;
        *reinterpret_cast<float4*>(dst + 8)  = e2;
        *reinterpret_cast<float4*>(dst + 12) = e3;
    }

    // ---- W1: u = [h, emb] @ W1 + b1 ; LN1 + relu -> act cols 0..127 ----
    {
        f32x4 acc[8] = {};
        gemm(ic<6>{}, ic<8>{}, 72, acc);
        float b1v[8], g1v[8], be1v[8];
        sfor<8>([&](auto NT) {
            b1v[NT.value]  = b1[NT.value * 16 + j];
            g1v[NT.value]  = g1[NT.value * 16 + j];
            be1v[NT.value] = be1[NT.value * 16 + j];
        });
        float su[4] = {}, sq[4] = {};
        sfor<8>([&](auto NT) { sfor<4>([&](auto R) {
            const float u = acc[NT.value][R.value] + b1v[NT.value];
            acc[NT.value][R.value] = u;
            su[R.value] += u; sq[R.value] += u * u;
        }); });
#pragma unroll
        for (int off = 1; off <= 8; off <<= 1) {
            sfor<4>([&](auto R) {
                su[R.value] += __shfl_xor(su[R.value], off, 64);
                sq[R.value] += __shfl_xor(sq[R.value], off, 64);
            });
        }
        float m[4], rs[4];
        sfor<4>([&](auto R) {
            m[R.value] = su[R.value] * (1.f / 128.f);
            const float var = sq[R.value] * (1.f / 128.f) - m[R.value] * m[R.value];
            rs[R.value] = rsqrtf(var + LNEPS);
        });
        sfor<8>([&](auto NT) { sfor<4>([&](auto R) {
            const float z = fmaxf((acc[NT.value][R.value] - m[R.value]) * rs[R.value]
                                  * g1v[NT.value] + be1v[NT.value], 0.f);
            act[(4 * gq + R.value) * ACTW + NT.value * 16 + j] = z;
        }); });
    }

    // ---- W2: v = z1 @ W2 + b2 ; LN2 + relu ; out = z2 @ Wo + bo ----
    {
        f32x4 acc[4] = {};
        gemm(ic<4>{}, ic<4>{}, 120, acc);
        float b2v[4], g2v[4], be2v[4], wov[4];
        sfor<4>([&](auto NT) {
            b2v[NT.value]  = b2[NT.value * 16 + j];
            g2v[NT.value]  = g2[NT.value * 16 + j];
            be2v[NT.value] = be2[NT.value * 16 + j];
            wov[NT.value]  = Wo[NT.value * 16 + j];
        });
        float su[4] = {}, sq[4] = {};
        sfor<4>([&](auto NT) { sfor<4>([&](auto R) {
            const float v = acc[NT.value][R.value] + b2v[NT.value];
            acc[NT.value][R.value] = v;
            su[R.value] += v; sq[R.value] += v * v;
        }); });
#pragma unroll
        for (int off = 1; off <= 8; off <<= 1) {
            sfor<4>([&](auto R) {
                su[R.value] += __shfl_xor(su[R.value], off, 64);
                sq[R.value] += __shfl_xor(sq[R.value], off, 64);
            });
        }
        float po[4];
        sfor<4>([&](auto R) {
            const float m   = su[R.value] * (1.f / 64.f);
            const float var = sq[R.value] * (1.f / 64.f) - m * m;
            const float rs  = rsqrtf(var + LNEPS);
            float p = 0.f;
            sfor<4>([&](auto NT) {
                p += fmaxf((acc[NT.value][R.value] - m) * rs * g2v[NT.value]
                           + be2v[NT.value], 0.f) * wov[NT.value];
            });
            po[R.value] = p;
        });
#pragma unroll
        for (int off = 1; off <= 8; off <<= 1) {
            sfor<4>([&](auto R) { po[R.value] += __shfl_xor(po[R.value], off, 64); });
        }
        const float bov = bo[0];
        if (j == 0 && gq < 2) {
            sfor<4>([&](auto R) {
                out[sbase + 4 * gq + R.value] = po[R.value] + bov;
            });
        }
    }
}

}  // namespace

extern "C" void kernel_launch(void* const* d_in, const int* in_sizes, int n_in,
                              void* d_out, int out_size, void* d_ws, size_t ws_size,
                              hipStream_t stream)
{
    const float* x    = (const float*)d_in[0];
    const int*   sid  = (const int*)d_in[1];
    // d_in[2] edge_index, d_in[3] edge_weight, d_in[8] gat_a: unused —
    // node-uniform broadcast + row-softmax makes the GAT aggregation collapse
    // to elu(h @ W) independent of the graph.
    const float* Wp   = (const float*)d_in[4];
    const float* bp   = (const float*)d_in[5];
    const float* emb  = (const float*)d_in[6];
    const float* gatW = (const float*)d_in[7];
    const float* W1   = (const float*)d_in[9];
    const float* b1   = (const float*)d_in[10];
    const float* g1   = (const float*)d_in[11];
    const float* be1  = (const float*)d_in[12];
    const float* W2   = (const float*)d_in[13];
    const float* b2   = (const float*)d_in[14];
    const float* g2   = (const float*)d_in[15];
    const float* be2  = (const float*)d_in[16];
    const float* Wo   = (const float*)d_in[17];
    const float* bo   = (const float*)d_in[18];
    float* out = (float*)d_out;

    __bf16* wsf = (__bf16*)d_ws;   // 136 frags * 1024 B = 139264 B << ws_size

    // 1) repack weights into per-lane MFMA B-fragments (bf16, RNE)
    pack_weights<<<dim3(136), dim3(64), 0, stream>>>(Wp, gatW, W1, W2, wsf);
    // 2) fused forward: 512 single-wave blocks, 8 samples each (2 blocks/CU)
    mfma_fused<<<dim3(4096 / SPW), dim3(64), 0, stream>>>(
        x, sid, wsf, bp, emb, b1, g1, be1, b2, g2, be2, Wo, bo, out);
}